// Round 1
// baseline (556.760 us; speedup 1.0000x reference)
//
#include <hip/hip_runtime.h>

typedef unsigned short ushort_t;
typedef short bf16x8 __attribute__((ext_vector_type(8)));
typedef float f32x4 __attribute__((ext_vector_type(4)));

#define DEV __device__ __forceinline__

DEV ushort_t f2bf(float f) {
  union { float f; unsigned int u; } v; v.f = f;
  unsigned int u = v.u;
  u = (u + 0x7FFFu + ((u >> 16) & 1u)) >> 16;
  return (ushort_t)u;
}
DEV float bf2f(ushort_t h) {
  union { unsigned int u; float f; } v; v.u = ((unsigned int)h) << 16;
  return v.f;
}
DEV f32x4 mfma16(bf16x8 a, bf16x8 b, f32x4 c) {
  return __builtin_amdgcn_mfma_f32_16x16x32_bf16(a, b, c, 0, 0, 0);
}

// ---------------------------------------------------------------------------
// Generic bf16 GEMM: C = A[M,K] * B[K,N] (+bias), B given pre-transposed as
// BT[N,K]. 128x128 block tile, 4 waves, each wave 64x64 via 4x4 MFMA tiles.
// Output either bf16 (Cb, with channel offset into a wider row) or fp32 (Cf).
// ---------------------------------------------------------------------------
__global__ __launch_bounds__(256)
void gemm_bt(const ushort_t* __restrict__ A, int lda,
             const ushort_t* __restrict__ BT,
             const float* __restrict__ bias,
             ushort_t* __restrict__ Cb, float* __restrict__ Cf,
             int ldc, int coff, int K)
{
  __shared__ __align__(16) ushort_t As[128 * 32];
  __shared__ __align__(16) ushort_t Bs[128 * 32];
  const int tid  = threadIdx.x;
  const int wave = tid >> 6, lane = tid & 63;
  const int quad = lane >> 4, r16 = lane & 15;
  const int m0 = blockIdx.x * 128, n0 = blockIdx.y * 128;
  const int wm = (wave >> 1) * 64, wn = (wave & 1) * 64;

  f32x4 acc[4][4];
#pragma unroll
  for (int i = 0; i < 4; ++i)
#pragma unroll
    for (int j = 0; j < 4; ++j) acc[i][j] = (f32x4){0.f, 0.f, 0.f, 0.f};

  for (int kc = 0; kc < K; kc += 32) {
#pragma unroll
    for (int pass = 0; pass < 2; ++pass) {
      int chunk = pass * 256 + tid;          // 512 chunks of 8 bf16 per tile
      int row = chunk >> 2, c8 = chunk & 3;
      *(uint4*)&As[chunk * 8] =
          *(const uint4*)&A[(size_t)(m0 + row) * lda + kc + c8 * 8];
      *(uint4*)&Bs[chunk * 8] =
          *(const uint4*)&BT[(size_t)(n0 + row) * K + kc + c8 * 8];
    }
    __syncthreads();
    bf16x8 af[4], bfr[4];
#pragma unroll
    for (int i = 0; i < 4; ++i) {
      af[i]  = *(const bf16x8*)&As[(wm + i * 16 + r16) * 32 + quad * 8];
      bfr[i] = *(const bf16x8*)&Bs[(wn + i * 16 + r16) * 32 + quad * 8];
    }
#pragma unroll
    for (int mi = 0; mi < 4; ++mi)
#pragma unroll
      for (int ni = 0; ni < 4; ++ni)
        acc[mi][ni] = mfma16(af[mi], bfr[ni], acc[mi][ni]);
    __syncthreads();
  }

  // Epilogue. C/D layout: col = lane&15, row = quad*4 + reg  [verified m89/m91]
#pragma unroll
  for (int mi = 0; mi < 4; ++mi) {
#pragma unroll
    for (int ni = 0; ni < 4; ++ni) {
      int col = n0 + wn + ni * 16 + r16;
      float bv = bias ? bias[col] : 0.f;
#pragma unroll
      for (int r = 0; r < 4; ++r) {
        int row = m0 + wm + mi * 16 + quad * 4 + r;
        float v = acc[mi][ni][r] + bv;
        if (Cf) Cf[(size_t)row * ldc + coff + col] = v;
        else    Cb[(size_t)row * ldc + coff + col] = f2bf(v);
      }
    }
  }
}

// ---------------------------------------------------------------------------
// Flash attention (full seq, head_dim=64). One wave = 16 query rows; block =
// 4 waves = 64 rows. Key tiles of 32 staged in LDS (K as [s][d], V transposed
// as [d][s]). S^T = K*Q^T via MFMA (Q fragment doubles as B-operand since A/B
// lane layouts coincide). P goes through LDS to reach A-operand layout.
// ---------------------------------------------------------------------------
__global__ __launch_bounds__(256)
void flash_attn(const ushort_t* __restrict__ Qb, int qs, int q_ch,
                const ushort_t* __restrict__ Kb, int ks, int k_ch,
                const ushort_t* __restrict__ Vb, int vs, int v_ch,
                ushort_t* __restrict__ Ob, int os, int o_ch,
                int N)
{
  __shared__ __align__(16) ushort_t Ks_s[32 * 64];
  __shared__ __align__(16) ushort_t VT[64 * 32];
  __shared__ __align__(16) ushort_t Pt[4][16 * 32];

  const int b = blockIdx.z, h = blockIdx.y;
  const int tid  = threadIdx.x;
  const int wave = tid >> 6, lane = tid & 63;
  const int quad = lane >> 4, c16 = lane & 15;

  const size_t qrow = (size_t)b * N + blockIdx.x * 64 + wave * 16 + c16;
  const ushort_t* qp = Qb + qrow * qs + q_ch + h * 64;
  bf16x8 qf0 = *(const bf16x8*)&qp[quad * 8];
  bf16x8 qf1 = *(const bf16x8*)&qp[32 + quad * 8];

  f32x4 oacc[4];
#pragma unroll
  for (int c = 0; c < 4; ++c) oacc[c] = (f32x4){0.f, 0.f, 0.f, 0.f};
  float m_cur = -1e30f, l_cur = 0.f;

  const int srow = tid >> 3, sd0 = (tid & 7) * 8;  // staging: 32 rows x 8 chunks

  for (int s0 = 0; s0 < N; s0 += 32) {
    __syncthreads();   // protect prev iteration's LDS reads from overwrite
    {
      const ushort_t* kp = Kb + ((size_t)b * N + s0 + srow) * ks + k_ch + h * 64 + sd0;
      *(uint4*)&Ks_s[srow * 64 + sd0] = *(const uint4*)kp;
      const ushort_t* vp = Vb + ((size_t)b * N + s0 + srow) * vs + v_ch + h * 64 + sd0;
      union { uint4 v; ushort_t u[8]; } vv; vv.v = *(const uint4*)vp;
#pragma unroll
      for (int j = 0; j < 8; ++j) VT[(sd0 + j) * 32 + srow] = vv.u[j];
    }
    __syncthreads();

    // S^T tiles: row = key (quad*4+reg), col = query (lane&15)
    f32x4 st[2];
#pragma unroll
    for (int sh = 0; sh < 2; ++sh) {
      bf16x8 kf0 = *(const bf16x8*)&Ks_s[(sh * 16 + c16) * 64 + quad * 8];
      bf16x8 kf1 = *(const bf16x8*)&Ks_s[(sh * 16 + c16) * 64 + 32 + quad * 8];
      f32x4 z = (f32x4){0.f, 0.f, 0.f, 0.f};
      z = mfma16(kf0, qf0, z);
      z = mfma16(kf1, qf1, z);
      st[sh] = z;
    }

    float sv[2][4];
    float mx = -1e30f;
#pragma unroll
    for (int sh = 0; sh < 2; ++sh)
#pragma unroll
      for (int r = 0; r < 4; ++r) {
        sv[sh][r] = st[sh][r] * 0.125f;
        mx = fmaxf(mx, sv[sh][r]);
      }
    mx = fmaxf(mx, __shfl_xor(mx, 16));
    mx = fmaxf(mx, __shfl_xor(mx, 32));
    float m_new = fmaxf(m_cur, mx);
    float alpha = __expf(m_cur - m_new);
    float tsum = 0.f;
#pragma unroll
    for (int sh = 0; sh < 2; ++sh)
#pragma unroll
      for (int r = 0; r < 4; ++r) {
        float p = __expf(sv[sh][r] - m_new);
        tsum += p;
        // P[q = c16][s = sh*16 + quad*4 + r]
        Pt[wave][c16 * 32 + sh * 16 + quad * 4 + r] = f2bf(p);
      }
    tsum += __shfl_xor(tsum, 16);
    tsum += __shfl_xor(tsum, 32);
    l_cur = l_cur * alpha + tsum;
    m_cur = m_new;

    __syncthreads();   // make P visible (and order intra-wave LDS RAW)

    // rescale O rows (O row q = quad*4+reg; alpha lives in lane c16==q)
#pragma unroll
    for (int r = 0; r < 4; ++r) {
      float ar = __shfl(alpha, quad * 4 + r);
#pragma unroll
      for (int c = 0; c < 4; ++c) oacc[c][r] *= ar;
    }
    bf16x8 pf = *(const bf16x8*)&Pt[wave][c16 * 32 + quad * 8];
#pragma unroll
    for (int c = 0; c < 4; ++c) {
      bf16x8 vf = *(const bf16x8*)&VT[(c * 16 + c16) * 32 + quad * 8];
      oacc[c] = mfma16(pf, vf, oacc[c]);
    }
  }

  // epilogue: divide by l per row, write bf16
#pragma unroll
  for (int r = 0; r < 4; ++r) {
    float lr = __shfl(l_cur, quad * 4 + r);
    float inv = 1.f / lr;
    size_t n = (size_t)blockIdx.x * 64 + wave * 16 + quad * 4 + r;
    ushort_t* op = Ob + ((size_t)b * N + n) * os + o_ch + h * 64;
#pragma unroll
    for (int c = 0; c < 4; ++c) op[c * 16 + c16] = f2bf(oacc[c][r] * inv);
  }
}

// ---------------------------------------------------------------------------
// hifi window attention: windows of 2x2 tokens, 4 heads. One wave per
// (batch, window, head); lane = head-dim channel. qkv layout per token:
// [3][4 heads][64].
// ---------------------------------------------------------------------------
__global__ __launch_bounds__(256)
void hifi_win(const ushort_t* __restrict__ qkv, ushort_t* __restrict__ out)
{
  const int bg = blockIdx.x;
  const int b = bg >> 8, g = bg & 255;
  const int head = threadIdx.x >> 6, lane = threadIdx.x & 63;
  const int gh = g >> 4, gw = g & 15;

  int n[4];
  float q[4], k[4], v[4];
#pragma unroll
  for (int t = 0; t < 4; ++t) {
    n[t] = (gh * 2 + (t >> 1)) * 32 + gw * 2 + (t & 1);
    size_t base = ((size_t)b * 1024 + n[t]) * 768 + head * 64 + lane;
    q[t] = bf2f(qkv[base]);
    k[t] = bf2f(qkv[base + 256]);
    v[t] = bf2f(qkv[base + 512]);
  }
  float sc[4][4];
#pragma unroll
  for (int t = 0; t < 4; ++t)
#pragma unroll
    for (int s = 0; s < 4; ++s) {
      float p = q[t] * k[s];
#pragma unroll
      for (int off = 32; off >= 1; off >>= 1) p += __shfl_xor(p, off);
      sc[t][s] = p * 0.125f;
    }
#pragma unroll
  for (int t = 0; t < 4; ++t) {
    float m = fmaxf(fmaxf(sc[t][0], sc[t][1]), fmaxf(sc[t][2], sc[t][3]));
    float p0 = __expf(sc[t][0] - m), p1 = __expf(sc[t][1] - m);
    float p2 = __expf(sc[t][2] - m), p3 = __expf(sc[t][3] - m);
    float sum = p0 + p1 + p2 + p3;
    float o = (p0 * v[0] + p1 * v[1] + p2 * v[2] + p3 * v[3]) / sum;
    out[((size_t)b * 1024 + n[t]) * 256 + head * 64 + lane] = f2bf(o);
  }
}

// W[K][N] fp32 row-major -> WT[N][K] bf16
__global__ void w_to_bf16t(const float* __restrict__ W, ushort_t* __restrict__ WT,
                           int K, int N)
{
  int idx = blockIdx.x * 256 + threadIdx.x;
  if (idx >= K * N) return;
  int n_i = idx / K, k_i = idx - n_i * K;
  WT[idx] = f2bf(W[(size_t)k_i * N + n_i]);
}

// xpe = bf16(x + pos_emb), vectorized x4
__global__ void add_pos(const float* __restrict__ x, const float* __restrict__ pos,
                        ushort_t* __restrict__ xpe)
{
  int idx = blockIdx.x * 256 + threadIdx.x;   // over total/4
  int e = idx * 4;
  float4 xv = *(const float4*)&x[e];
  float4 pv = *(const float4*)&pos[e & (512 * 1024 - 1)];
  uint2 pk;
  pk.x = (unsigned)f2bf(xv.x + pv.x) | ((unsigned)f2bf(xv.y + pv.y) << 16);
  pk.y = (unsigned)f2bf(xv.z + pv.z) | ((unsigned)f2bf(xv.w + pv.w) << 16);
  *(uint2*)&xpe[e] = pk;
}

extern "C" void kernel_launch(void* const* d_in, const int* in_sizes, int n_in,
                              void* d_out, int out_size, void* d_ws, size_t ws_size,
                              hipStream_t stream)
{
  const float* x         = (const float*)d_in[0];
  const float* pos       = (const float*)d_in[1];
  const float* l_q_w     = (const float*)d_in[2];
  const float* l_kv_w    = (const float*)d_in[3];
  const float* l_proj_w  = (const float*)d_in[4];
  const float* l_proj_b  = (const float*)d_in[5];
  const float* h_qkv_w   = (const float*)d_in[6];
  const float* h_proj_w  = (const float*)d_in[7];
  const float* h_proj_b  = (const float*)d_in[8];
  const float* in_proj_w = (const float*)d_in[9];
  const float* in_proj_b = (const float*)d_in[10];
  const float* out_proj_w= (const float*)d_in[11];
  const float* out_proj_b= (const float*)d_in[12];
  float* out = (float*)d_out;

  char* ws = (char*)d_ws;
  ushort_t* xpe = (ushort_t*)(ws);                       // 16 MB
  ushort_t* y   = (ushort_t*)(ws + (size_t)16777216);    // 16 MB
  ushort_t* rA  = (ushort_t*)(ws + (size_t)33554432);    // 48 MB (qkv scratch)
  ushort_t* rB  = (ushort_t*)(ws + (size_t)83886080);    // 16 MB (attn out)
  ushort_t* wb  = (ushort_t*)(ws + (size_t)100663296);   // ~4 MB bf16 weights

  ushort_t* h_qkvT   = wb;                  // [768][512]
  ushort_t* h_projT  = wb + 393216;         // [256][256]
  ushort_t* l_qT     = wb + 458752;         // [256][512]
  ushort_t* l_kvT    = wb + 589824;         // [512][512]
  ushort_t* l_projT  = wb + 851968;         // [256][256]
  ushort_t* in_projT = wb + 917504;         // [1536][512]
  ushort_t* out_projT= wb + 1703936;        // [512][512]

  auto tr = [&](const float* W, ushort_t* WT, int K, int N) {
    int tot = K * N;
    w_to_bf16t<<<dim3((tot + 255) / 256), dim3(256), 0, stream>>>(W, WT, K, N);
  };
  tr(h_qkv_w,   h_qkvT,   512, 768);
  tr(h_proj_w,  h_projT,  256, 256);
  tr(l_q_w,     l_qT,     512, 256);
  tr(l_kv_w,    l_kvT,    512, 512);
  tr(l_proj_w,  l_projT,  256, 256);
  tr(in_proj_w, in_projT, 512, 1536);
  tr(out_proj_w,out_projT,512, 512);

  add_pos<<<dim3(8192), dim3(256), 0, stream>>>(x, pos, xpe);

  const int M = 16384;
  // 1. hifi qkv: [M,512] x [512,768] -> rA bf16
  gemm_bt<<<dim3(M / 128, 6), dim3(256), 0, stream>>>(
      xpe, 512, h_qkvT, nullptr, rA, nullptr, 768, 0, 512);
  // 2. hifi window attention -> rB [M,256]
  hifi_win<<<dim3(4096), dim3(256), 0, stream>>>(rA, rB);
  // 3. hifi proj -> y[:, 0:256]
  gemm_bt<<<dim3(M / 128, 2), dim3(256), 0, stream>>>(
      rB, 256, h_projT, h_proj_b, y, nullptr, 512, 0, 256);
  // 4. lofi q -> rA [M,256]
  gemm_bt<<<dim3(M / 128, 2), dim3(256), 0, stream>>>(
      xpe, 512, l_qT, nullptr, rA, nullptr, 256, 0, 512);
  // 5. lofi kv -> rA + M*256 [M,512]
  ushort_t* lkv = rA + (size_t)M * 256;
  gemm_bt<<<dim3(M / 128, 4), dim3(256), 0, stream>>>(
      xpe, 512, l_kvT, nullptr, lkv, nullptr, 512, 0, 512);
  // 6. lofi attention (4 heads) -> rB [M,256]
  flash_attn<<<dim3(16, 4, 16), dim3(256), 0, stream>>>(
      rA, 256, 0, lkv, 512, 0, lkv, 512, 256, rB, 256, 0, 1024);
  // 7. lofi proj -> y[:, 256:512]
  gemm_bt<<<dim3(M / 128, 2), dim3(256), 0, stream>>>(
      rB, 256, l_projT, l_proj_b, y, nullptr, 512, 256, 256);
  // 8. mha qkv: [M,512] x [512,1536] -> rA
  gemm_bt<<<dim3(M / 128, 12), dim3(256), 0, stream>>>(
      y, 512, in_projT, in_proj_b, rA, nullptr, 1536, 0, 512);
  // 9. mha attention (8 heads) -> rB [M,512]
  flash_attn<<<dim3(16, 8, 16), dim3(256), 0, stream>>>(
      rA, 1536, 0, rA, 1536, 512, rA, 1536, 1024, rB, 512, 0, 1024);
  // 10. out proj -> d_out fp32
  gemm_bt<<<dim3(M / 128, 4), dim3(256), 0, stream>>>(
      rB, 512, out_projT, out_proj_b, nullptr, out, 512, 0, 512);
}

// Round 2
// 432.099 us; speedup vs baseline: 1.2885x; 1.2885x over previous
//
#include <hip/hip_runtime.h>

typedef unsigned short ushort_t;
typedef short bf16x8 __attribute__((ext_vector_type(8)));
typedef float f32x4 __attribute__((ext_vector_type(4)));

#define DEV __device__ __forceinline__

DEV ushort_t f2bf(float f) {
  union { float f; unsigned int u; } v; v.f = f;
  unsigned int u = v.u;
  u = (u + 0x7FFFu + ((u >> 16) & 1u)) >> 16;
  return (ushort_t)u;
}
DEV float bf2f(ushort_t h) {
  union { unsigned int u; float f; } v; v.u = ((unsigned int)h) << 16;
  return v.f;
}
DEV f32x4 mfma16(bf16x8 a, bf16x8 b, f32x4 c) {
  return __builtin_amdgcn_mfma_f32_16x16x32_bf16(a, b, c, 0, 0, 0);
}
typedef __attribute__((address_space(3))) void lds_void;
typedef const __attribute__((address_space(1))) void glb_void;
DEV void gl_lds16(const void* g, void* l) {
  __builtin_amdgcn_global_load_lds((glb_void*)g, (lds_void*)l, 16, 0, 0);
}

// ---------------------------------------------------------------------------
// bf16 GEMM: C = A[M,K] * BT[N,K]^T (+bias). 128x128 tile, 4 waves, 4x4 MFMA
// per wave. Staging via global_load_lds width=16 (m97 pattern).
// ---------------------------------------------------------------------------
__global__ __launch_bounds__(256)
void gemm_bt(const ushort_t* __restrict__ A, int lda,
             const ushort_t* __restrict__ BT,
             const float* __restrict__ bias,
             ushort_t* __restrict__ Cb, float* __restrict__ Cf,
             int ldc, int coff, int K)
{
  __shared__ __align__(16) ushort_t As[128 * 32];
  __shared__ __align__(16) ushort_t Bs[128 * 32];
  const int tid  = threadIdx.x;
  const int wave = tid >> 6, lane = tid & 63;
  const int quad = lane >> 4, r16 = lane & 15;
  const int m0 = blockIdx.x * 128, n0 = blockIdx.y * 128;
  const int wm = (wave >> 1) * 64, wn = (wave & 1) * 64;

  f32x4 acc[4][4];
#pragma unroll
  for (int i = 0; i < 4; ++i)
#pragma unroll
    for (int j = 0; j < 4; ++j) acc[i][j] = (f32x4){0.f, 0.f, 0.f, 0.f};

  for (int kc = 0; kc < K; kc += 32) {
#pragma unroll
    for (int p = 0; p < 4; ++p) {
      int wp = p * 4 + wave;                 // 0..15; 0..7 -> As, 8..15 -> Bs
      int lc = ((wp & 7) << 6) + lane;       // chunk 0..511 within array
      int row = lc >> 2, e8 = (lc & 3) * 8;
      if (wp < 8) gl_lds16(&A[(size_t)(m0 + row) * lda + kc + e8], &As[lc * 8]);
      else        gl_lds16(&BT[(size_t)(n0 + row) * K  + kc + e8], &Bs[lc * 8]);
    }
    __syncthreads();
    bf16x8 af[4], bfr[4];
#pragma unroll
    for (int i = 0; i < 4; ++i) {
      af[i]  = *(const bf16x8*)&As[(wm + i * 16 + r16) * 32 + quad * 8];
      bfr[i] = *(const bf16x8*)&Bs[(wn + i * 16 + r16) * 32 + quad * 8];
    }
#pragma unroll
    for (int mi = 0; mi < 4; ++mi)
#pragma unroll
      for (int ni = 0; ni < 4; ++ni)
        acc[mi][ni] = mfma16(af[mi], bfr[ni], acc[mi][ni]);
    __syncthreads();
  }

  // C/D layout: col = lane&15, row = quad*4 + reg  [m89/m91]
#pragma unroll
  for (int mi = 0; mi < 4; ++mi) {
#pragma unroll
    for (int ni = 0; ni < 4; ++ni) {
      int col = n0 + wn + ni * 16 + r16;
      float bv = bias ? bias[col] : 0.f;
#pragma unroll
      for (int r = 0; r < 4; ++r) {
        int row = m0 + wm + mi * 16 + quad * 4 + r;
        float v = acc[mi][ni][r] + bv;
        if (Cf) Cf[(size_t)row * ldc + coff + col] = v;
        else    Cb[(size_t)row * ldc + coff + col] = f2bf(v);
      }
    }
  }
}

// ---------------------------------------------------------------------------
// Flash attention v2. Block = 4 waves; wave = 32 queries (2x16 tiles);
// block = 128 queries. Key tile = 64, staged via global_load_lds into
// K halves [64s][32d] and V^T halves [64d][32s] (64B-stride LDS rows).
// P routes through padded LDS (72-ushort rows, packed b64 writes).
// ---------------------------------------------------------------------------
__global__ __launch_bounds__(256)
void flash_attn2(const ushort_t* __restrict__ Q, int qs, int q_ch,
                 const ushort_t* __restrict__ Kg, int ks, int k_ch,
                 const ushort_t* __restrict__ vT,
                 ushort_t* __restrict__ O, int os, int o_ch,
                 int N)
{
  __shared__ __align__(16) ushort_t Ka[64 * 32], Kb2[64 * 32];
  __shared__ __align__(16) ushort_t Va[64 * 32], Vb2[64 * 32];
  __shared__ __align__(16) ushort_t Pt[4][32 * 72];

  const int b = blockIdx.z, h = blockIdx.y, H = gridDim.y;
  const int tid = threadIdx.x, wave = tid >> 6, lane = tid & 63;
  const int quad = lane >> 4, c16 = lane & 15;
  const int q0 = blockIdx.x * 128 + wave * 32;

  bf16x8 qf[2][2];
#pragma unroll
  for (int qt = 0; qt < 2; ++qt) {
    const ushort_t* qp = Q + ((size_t)b * N + q0 + qt * 16 + c16) * qs + q_ch + h * 64;
    qf[qt][0] = *(const bf16x8*)&qp[quad * 8];
    qf[qt][1] = *(const bf16x8*)&qp[32 + quad * 8];
  }
  const ushort_t* kbase = Kg + ((size_t)b * N) * ks + k_ch + h * 64;
  const ushort_t* vbase = vT + ((size_t)(b * H + h) * 64) * N;

  f32x4 oacc[2][4];
#pragma unroll
  for (int qt = 0; qt < 2; ++qt)
#pragma unroll
    for (int dt = 0; dt < 4; ++dt) oacc[qt][dt] = (f32x4){0.f, 0.f, 0.f, 0.f};
  float m_cur[2] = {-1e30f, -1e30f}, l_cur[2] = {0.f, 0.f};

  for (int s0 = 0; s0 < N; s0 += 64) {
    __syncthreads();                           // protect K/V/Pt from prev readers
#pragma unroll
    for (int p = 0; p < 4; ++p) {
      int wp = p * 4 + wave;                   // 0..15
      int lc = ((wp & 3) << 6) + lane;         // 0..255 within a half-array
      int row = lc >> 2, e8 = (lc & 3) * 8;
      if (wp < 4)       gl_lds16(kbase + (size_t)(s0 + row) * ks + e8,      &Ka[lc * 8]);
      else if (wp < 8)  gl_lds16(kbase + (size_t)(s0 + row) * ks + 32 + e8, &Kb2[lc * 8]);
      else if (wp < 12) gl_lds16(vbase + (size_t)row * N + s0 + e8,         &Va[lc * 8]);
      else              gl_lds16(vbase + (size_t)row * N + s0 + 32 + e8,    &Vb2[lc * 8]);
    }
    __syncthreads();                           // staging complete

    // S^T tiles: A = K rows (m = key), B = Q rows (n = query)
    f32x4 st[4][2];
#pragma unroll
    for (int si = 0; si < 4; ++si) {
      bf16x8 kf0 = *(const bf16x8*)&Ka[(si * 16 + c16) * 32 + quad * 8];
      bf16x8 kf1 = *(const bf16x8*)&Kb2[(si * 16 + c16) * 32 + quad * 8];
#pragma unroll
      for (int qt = 0; qt < 2; ++qt) {
        f32x4 z = (f32x4){0.f, 0.f, 0.f, 0.f};
        z = mfma16(kf0, qf[qt][0], z);
        z = mfma16(kf1, qf[qt][1], z);
        st[si][qt] = z;
      }
    }

#pragma unroll
    for (int qt = 0; qt < 2; ++qt) {
      float mx = -1e30f;
#pragma unroll
      for (int si = 0; si < 4; ++si)
#pragma unroll
        for (int r = 0; r < 4; ++r) {
          float v = st[si][qt][r] * 0.125f;
          st[si][qt][r] = v;
          mx = fmaxf(mx, v);
        }
      mx = fmaxf(mx, __shfl_xor(mx, 16));
      mx = fmaxf(mx, __shfl_xor(mx, 32));
      float m_new = fmaxf(m_cur[qt], mx);
      float alpha = __expf(m_cur[qt] - m_new);
      float tsum = 0.f;
#pragma unroll
      for (int si = 0; si < 4; ++si) {
        float p0 = __expf(st[si][qt][0] - m_new);
        float p1 = __expf(st[si][qt][1] - m_new);
        float p2 = __expf(st[si][qt][2] - m_new);
        float p3 = __expf(st[si][qt][3] - m_new);
        tsum += (p0 + p1) + (p2 + p3);
        uint2 pk;
        pk.x = (unsigned)f2bf(p0) | ((unsigned)f2bf(p1) << 16);
        pk.y = (unsigned)f2bf(p2) | ((unsigned)f2bf(p3) << 16);
        // P[q = qt*16+c16][s = si*16 + quad*4 .. +3], padded row stride 72
        *(uint2*)&Pt[wave][(qt * 16 + c16) * 72 + si * 16 + quad * 4] = pk;
      }
      tsum += __shfl_xor(tsum, 16);
      tsum += __shfl_xor(tsum, 32);
      l_cur[qt] = l_cur[qt] * alpha + tsum;
      m_cur[qt] = m_new;
      // rescale O rows (row q = quad*4+r; alpha valid in all lanes w/ c16 == q)
#pragma unroll
      for (int r = 0; r < 4; ++r) {
        float ar = __shfl(alpha, quad * 4 + r);
#pragma unroll
        for (int dt = 0; dt < 4; ++dt) oacc[qt][dt][r] *= ar;
      }
    }
    __syncthreads();                           // P visible for PV

#pragma unroll
    for (int qt = 0; qt < 2; ++qt) {
      bf16x8 pf0 = *(const bf16x8*)&Pt[wave][(qt * 16 + c16) * 72 + quad * 8];
      bf16x8 pf1 = *(const bf16x8*)&Pt[wave][(qt * 16 + c16) * 72 + 32 + quad * 8];
#pragma unroll
      for (int dt = 0; dt < 4; ++dt) {
        bf16x8 vf0 = *(const bf16x8*)&Va[(dt * 16 + c16) * 32 + quad * 8];
        bf16x8 vf1 = *(const bf16x8*)&Vb2[(dt * 16 + c16) * 32 + quad * 8];
        oacc[qt][dt] = mfma16(pf0, vf0, oacc[qt][dt]);
        oacc[qt][dt] = mfma16(pf1, vf1, oacc[qt][dt]);
      }
    }
  }

#pragma unroll
  for (int qt = 0; qt < 2; ++qt)
#pragma unroll
    for (int r = 0; r < 4; ++r) {
      float inv = 1.f / __shfl(l_cur[qt], quad * 4 + r);
      size_t row = q0 + qt * 16 + quad * 4 + r;
      ushort_t* op = O + ((size_t)b * N + row) * os + o_ch + h * 64;
#pragma unroll
      for (int dt = 0; dt < 4; ++dt)
        op[dt * 16 + c16] = f2bf(oacc[qt][dt][r] * inv);
    }
}

// ---------------------------------------------------------------------------
// V transpose: in [B*N][ld] bf16 (channel offset ch, head h) -> out [B*H][64][N]
// ---------------------------------------------------------------------------
__global__ __launch_bounds__(256)
void transpose_v(const ushort_t* __restrict__ in, int ld, int ch,
                 ushort_t* __restrict__ out, int N, int H)
{
  __shared__ __align__(16) ushort_t T[64][72];
  const int s0 = blockIdx.x * 64, h = blockIdx.y, b = blockIdx.z;
  const int tid = threadIdx.x;
#pragma unroll
  for (int p = 0; p < 2; ++p) {
    int c = p * 256 + tid;                     // 512 chunks of 8
    int sr = c >> 3, d0 = (c & 7) * 8;
    *(uint4*)&T[sr][d0] =
        *(const uint4*)&in[((size_t)b * N + s0 + sr) * ld + ch + h * 64 + d0];
  }
  __syncthreads();
  const int d = tid >> 2, sp = (tid & 3) * 16;
  union { uint4 v; ushort_t u[8]; } A, B;
#pragma unroll
  for (int j = 0; j < 8; ++j) { A.u[j] = T[sp + j][d]; B.u[j] = T[sp + 8 + j][d]; }
  ushort_t* op = out + ((size_t)(b * H + h) * 64 + d) * N + s0 + sp;
  *(uint4*)&op[0] = A.v;
  *(uint4*)&op[8] = B.v;
}

// ---------------------------------------------------------------------------
// hifi window attention (2x2 windows, 4 heads). Unchanged from R0.
// ---------------------------------------------------------------------------
__global__ __launch_bounds__(256)
void hifi_win(const ushort_t* __restrict__ qkv, ushort_t* __restrict__ out)
{
  const int bg = blockIdx.x;
  const int b = bg >> 8, g = bg & 255;
  const int head = threadIdx.x >> 6, lane = threadIdx.x & 63;
  const int gh = g >> 4, gw = g & 15;

  int n[4];
  float q[4], k[4], v[4];
#pragma unroll
  for (int t = 0; t < 4; ++t) {
    n[t] = (gh * 2 + (t >> 1)) * 32 + gw * 2 + (t & 1);
    size_t base = ((size_t)b * 1024 + n[t]) * 768 + head * 64 + lane;
    q[t] = bf2f(qkv[base]);
    k[t] = bf2f(qkv[base + 256]);
    v[t] = bf2f(qkv[base + 512]);
  }
  float sc[4][4];
#pragma unroll
  for (int t = 0; t < 4; ++t)
#pragma unroll
    for (int s = 0; s < 4; ++s) {
      float p = q[t] * k[s];
#pragma unroll
      for (int off = 32; off >= 1; off >>= 1) p += __shfl_xor(p, off);
      sc[t][s] = p * 0.125f;
    }
#pragma unroll
  for (int t = 0; t < 4; ++t) {
    float m = fmaxf(fmaxf(sc[t][0], sc[t][1]), fmaxf(sc[t][2], sc[t][3]));
    float p0 = __expf(sc[t][0] - m), p1 = __expf(sc[t][1] - m);
    float p2 = __expf(sc[t][2] - m), p3 = __expf(sc[t][3] - m);
    float sum = p0 + p1 + p2 + p3;
    float o = (p0 * v[0] + p1 * v[1] + p2 * v[2] + p3 * v[3]) / sum;
    out[((size_t)b * 1024 + n[t]) * 256 + head * 64 + lane] = f2bf(o);
  }
}

// ---------------------------------------------------------------------------
// Weight prep: W[K][N] fp32 -> WT[N][K] bf16, LDS-tiled transpose (64x64).
// ---------------------------------------------------------------------------
__global__ __launch_bounds__(256)
void w_to_bf16t(const float* __restrict__ W, ushort_t* __restrict__ WT,
                int K, int N)
{
  __shared__ float T[64][65];
  const int k0 = blockIdx.x * 64, n0 = blockIdx.y * 64;
  const int tid = threadIdx.x;
#pragma unroll
  for (int p = 0; p < 4; ++p) {
    int c = p * 256 + tid;                     // 1024 float4 chunks
    int kr = c >> 4, f4 = (c & 15) * 4;
    float4 v = *(const float4*)&W[(size_t)(k0 + kr) * N + n0 + f4];
    T[f4 + 0][kr] = v.x; T[f4 + 1][kr] = v.y;
    T[f4 + 2][kr] = v.z; T[f4 + 3][kr] = v.w;
  }
  __syncthreads();
  const int nl = tid >> 2, kp = (tid & 3) * 16;
  union { uint4 v; ushort_t u[8]; } A, B;
#pragma unroll
  for (int j = 0; j < 8; ++j) {
    A.u[j] = f2bf(T[nl][kp + j]);
    B.u[j] = f2bf(T[nl][kp + 8 + j]);
  }
  ushort_t* op = WT + (size_t)(n0 + nl) * K + k0 + kp;
  *(uint4*)&op[0] = A.v;
  *(uint4*)&op[8] = B.v;
}

// xpe = bf16(x + pos_emb), vectorized x4
__global__ void add_pos(const float* __restrict__ x, const float* __restrict__ pos,
                        ushort_t* __restrict__ xpe)
{
  int idx = blockIdx.x * 256 + threadIdx.x;
  int e = idx * 4;
  float4 xv = *(const float4*)&x[e];
  float4 pv = *(const float4*)&pos[e & (512 * 1024 - 1)];
  uint2 pk;
  pk.x = (unsigned)f2bf(xv.x + pv.x) | ((unsigned)f2bf(xv.y + pv.y) << 16);
  pk.y = (unsigned)f2bf(xv.z + pv.z) | ((unsigned)f2bf(xv.w + pv.w) << 16);
  *(uint2*)&xpe[e] = pk;
}

extern "C" void kernel_launch(void* const* d_in, const int* in_sizes, int n_in,
                              void* d_out, int out_size, void* d_ws, size_t ws_size,
                              hipStream_t stream)
{
  const float* x         = (const float*)d_in[0];
  const float* pos       = (const float*)d_in[1];
  const float* l_q_w     = (const float*)d_in[2];
  const float* l_kv_w    = (const float*)d_in[3];
  const float* l_proj_w  = (const float*)d_in[4];
  const float* l_proj_b  = (const float*)d_in[5];
  const float* h_qkv_w   = (const float*)d_in[6];
  const float* h_proj_w  = (const float*)d_in[7];
  const float* h_proj_b  = (const float*)d_in[8];
  const float* in_proj_w = (const float*)d_in[9];
  const float* in_proj_b = (const float*)d_in[10];
  const float* out_proj_w= (const float*)d_in[11];
  const float* out_proj_b= (const float*)d_in[12];
  float* out = (float*)d_out;

  char* ws = (char*)d_ws;
  ushort_t* xpe = (ushort_t*)(ws);                       // 16 MB
  ushort_t* y   = (ushort_t*)(ws + (size_t)16777216);    // 16 MB
  ushort_t* rA  = (ushort_t*)(ws + (size_t)33554432);    // 48 MB
  ushort_t* rB  = (ushort_t*)(ws + (size_t)83886080);    // 16 MB
  ushort_t* wb  = (ushort_t*)(ws + (size_t)100663296);   // ~4 MB bf16 weights

  ushort_t* h_qkvT   = wb;                  // [768][512]
  ushort_t* h_projT  = wb + 393216;         // [256][256]
  ushort_t* l_qT     = wb + 458752;         // [256][512]
  ushort_t* l_kvT    = wb + 589824;         // [512][512]
  ushort_t* l_projT  = wb + 851968;         // [256][256]
  ushort_t* in_projT = wb + 917504;         // [1536][512]
  ushort_t* out_projT= wb + 1703936;        // [512][512]

  const int M = 16384;
  ushort_t* lkv   = rA + (size_t)M * 256;   // lofi kv [M,512]
  ushort_t* vT_lo = rA + (size_t)M * 768;   // [16][4][64][1024] = 8 MB
  ushort_t* vT_m  = rB;                     // [16][8][64][1024] = 16 MB

  auto tr = [&](const float* W, ushort_t* WT, int K, int N) {
    w_to_bf16t<<<dim3(K / 64, N / 64), dim3(256), 0, stream>>>(W, WT, K, N);
  };
  tr(h_qkv_w,   h_qkvT,   512, 768);
  tr(h_proj_w,  h_projT,  256, 256);
  tr(l_q_w,     l_qT,     512, 256);
  tr(l_kv_w,    l_kvT,    512, 512);
  tr(l_proj_w,  l_projT,  256, 256);
  tr(in_proj_w, in_projT, 512, 1536);
  tr(out_proj_w,out_projT,512, 512);

  add_pos<<<dim3(8192), dim3(256), 0, stream>>>(x, pos, xpe);

  // 1. hifi qkv: [M,512] x [512,768] -> rA
  gemm_bt<<<dim3(M / 128, 6), dim3(256), 0, stream>>>(
      xpe, 512, h_qkvT, nullptr, rA, nullptr, 768, 0, 512);
  // 2. hifi window attention -> rB [M,256]
  hifi_win<<<dim3(4096), dim3(256), 0, stream>>>(rA, rB);
  // 3. hifi proj -> y[:, 0:256]
  gemm_bt<<<dim3(M / 128, 2), dim3(256), 0, stream>>>(
      rB, 256, h_projT, h_proj_b, y, nullptr, 512, 0, 256);
  // 4. lofi q -> rA [M,256]
  gemm_bt<<<dim3(M / 128, 2), dim3(256), 0, stream>>>(
      xpe, 512, l_qT, nullptr, rA, nullptr, 256, 0, 512);
  // 5. lofi kv -> lkv [M,512]
  gemm_bt<<<dim3(M / 128, 4), dim3(256), 0, stream>>>(
      xpe, 512, l_kvT, nullptr, lkv, nullptr, 512, 0, 512);
  // 5b. transpose lofi V (lkv cols 256..511) -> vT_lo
  transpose_v<<<dim3(16, 4, 16), dim3(256), 0, stream>>>(
      lkv, 512, 256, vT_lo, 1024, 4);
  // 6. lofi attention (4 heads) -> rB [M,256]
  flash_attn2<<<dim3(8, 4, 16), dim3(256), 0, stream>>>(
      rA, 256, 0, lkv, 512, 0, vT_lo, rB, 256, 0, 1024);
  // 7. lofi proj -> y[:, 256:512]
  gemm_bt<<<dim3(M / 128, 2), dim3(256), 0, stream>>>(
      rB, 256, l_projT, l_proj_b, y, nullptr, 512, 256, 256);
  // 8. mha qkv: [M,512] x [512,1536] -> rA
  gemm_bt<<<dim3(M / 128, 12), dim3(256), 0, stream>>>(
      y, 512, in_projT, in_proj_b, rA, nullptr, 1536, 0, 512);
  // 8b. transpose mha V (rA cols 1024..1535) -> vT_m (rB is free now)
  transpose_v<<<dim3(16, 8, 16), dim3(256), 0, stream>>>(
      rA, 1536, 1024, vT_m, 1024, 8);
  // 9. mha attention (8 heads) -> xpe [M,512] (xpe free after step 5)
  flash_attn2<<<dim3(8, 8, 16), dim3(256), 0, stream>>>(
      rA, 1536, 0, rA, 1536, 512, vT_m, xpe, 512, 0, 1024);
  // 10. out proj -> d_out fp32
  gemm_bt<<<dim3(M / 128, 4), dim3(256), 0, stream>>>(
      xpe, 512, out_projT, out_proj_b, nullptr, out, 512, 0, 512);
}

// Round 3
// 394.883 us; speedup vs baseline: 1.4099x; 1.0942x over previous
//
#include <hip/hip_runtime.h>

typedef unsigned short ushort_t;
typedef short bf16x8 __attribute__((ext_vector_type(8)));
typedef float f32x4 __attribute__((ext_vector_type(4)));

#define DEV __device__ __forceinline__

// round-half-up bf16 (2 ops) — vs 5-op RNE; max divergence from RNE = ties only
DEV ushort_t f2bf(float f) {
  return (ushort_t)((__float_as_uint(f) + 0x8000u) >> 16);
}
// pack two floats -> 2 bf16 in one u32 (3 ops: add, add, v_perm_b32)
DEV unsigned pk_bf16(float lo, float hi) {
  unsigned a = __float_as_uint(lo) + 0x8000u;
  unsigned b = __float_as_uint(hi) + 0x8000u;
  return __builtin_amdgcn_perm(b, a, 0x07060302);  // {b.hi16, a.hi16}
}
DEV float bf2f(ushort_t h) {
  union { unsigned int u; float f; } v; v.u = ((unsigned int)h) << 16;
  return v.f;
}
DEV f32x4 mfma16(bf16x8 a, bf16x8 b, f32x4 c) {
  return __builtin_amdgcn_mfma_f32_16x16x32_bf16(a, b, c, 0, 0, 0);
}
typedef __attribute__((address_space(3))) void lds_void;
typedef const __attribute__((address_space(1))) void glb_void;
DEV void gl_lds16(const void* g, void* l) {
  __builtin_amdgcn_global_load_lds((glb_void*)g, (lds_void*)l, 16, 0, 0);
}

// ---------------------------------------------------------------------------
// bf16 GEMM: C = A[M,K] * BT[N,K]^T (+bias). 128x128 tile, 4 waves, 4x4 MFMA.
// Columns in [sc_lo, sc_hi) are scaled by 0.125 after bias (Q pre-scaling).
// ---------------------------------------------------------------------------
__global__ __launch_bounds__(256)
void gemm_bt(const ushort_t* __restrict__ A, int lda,
             const ushort_t* __restrict__ BT,
             const float* __restrict__ bias,
             ushort_t* __restrict__ Cb, float* __restrict__ Cf,
             int ldc, int coff, int K, int sc_lo, int sc_hi)
{
  __shared__ __align__(16) ushort_t As[128 * 32];
  __shared__ __align__(16) ushort_t Bs[128 * 32];
  const int tid  = threadIdx.x;
  const int wave = tid >> 6, lane = tid & 63;
  const int quad = lane >> 4, r16 = lane & 15;
  const int m0 = blockIdx.x * 128, n0 = blockIdx.y * 128;
  const int wm = (wave >> 1) * 64, wn = (wave & 1) * 64;

  f32x4 acc[4][4];
#pragma unroll
  for (int i = 0; i < 4; ++i)
#pragma unroll
    for (int j = 0; j < 4; ++j) acc[i][j] = (f32x4){0.f, 0.f, 0.f, 0.f};

  for (int kc = 0; kc < K; kc += 32) {
#pragma unroll
    for (int p = 0; p < 4; ++p) {
      int wp = p * 4 + wave;                 // 0..15; 0..7 -> As, 8..15 -> Bs
      int lc = ((wp & 7) << 6) + lane;       // chunk 0..511 within array
      int row = lc >> 2, e8 = (lc & 3) * 8;
      if (wp < 8) gl_lds16(&A[(size_t)(m0 + row) * lda + kc + e8], &As[lc * 8]);
      else        gl_lds16(&BT[(size_t)(n0 + row) * K  + kc + e8], &Bs[lc * 8]);
    }
    __syncthreads();
    bf16x8 af[4], bfr[4];
#pragma unroll
    for (int i = 0; i < 4; ++i) {
      af[i]  = *(const bf16x8*)&As[(wm + i * 16 + r16) * 32 + quad * 8];
      bfr[i] = *(const bf16x8*)&Bs[(wn + i * 16 + r16) * 32 + quad * 8];
    }
#pragma unroll
    for (int mi = 0; mi < 4; ++mi)
#pragma unroll
      for (int ni = 0; ni < 4; ++ni)
        acc[mi][ni] = mfma16(af[mi], bfr[ni], acc[mi][ni]);
    __syncthreads();
  }

  // C/D layout: col = lane&15, row = quad*4 + reg  [m89/m91]
#pragma unroll
  for (int mi = 0; mi < 4; ++mi) {
#pragma unroll
    for (int ni = 0; ni < 4; ++ni) {
      int col = n0 + wn + ni * 16 + r16;
      float bv = bias ? bias[col] : 0.f;
      float s = (col >= sc_lo && col < sc_hi) ? 0.125f : 1.0f;
#pragma unroll
      for (int r = 0; r < 4; ++r) {
        int row = m0 + wm + mi * 16 + quad * 4 + r;
        float v = (acc[mi][ni][r] + bv) * s;
        if (Cf) Cf[(size_t)row * ldc + coff + col] = v;
        else    Cb[(size_t)row * ldc + coff + col] = f2bf(v);
      }
    }
  }
}

// ---------------------------------------------------------------------------
// Flash attention v3. Block = 4 waves x 32 queries. Key tile 64 staged via
// global_load_lds (K halves [64s][32d], V^T halves [64d][32s]). Q arrives
// PRE-SCALED by 0.125. P through padded LDS (72-ushort rows, packed writes).
// ---------------------------------------------------------------------------
__global__ __launch_bounds__(256)
void flash_attn3(const ushort_t* __restrict__ Q, int qs, int q_ch,
                 const ushort_t* __restrict__ Kg, int ks, int k_ch,
                 const ushort_t* __restrict__ vT,
                 ushort_t* __restrict__ O, int os, int o_ch,
                 int N)
{
  __shared__ __align__(16) ushort_t Ka[64 * 32], Kb2[64 * 32];
  __shared__ __align__(16) ushort_t Va[64 * 32], Vb2[64 * 32];
  __shared__ __align__(16) ushort_t Pt[4][32 * 72];

  const int b = blockIdx.z, h = blockIdx.y, H = gridDim.y;
  const int tid = threadIdx.x, wave = tid >> 6, lane = tid & 63;
  const int quad = lane >> 4, c16 = lane & 15;
  const int q0 = blockIdx.x * 128 + wave * 32;

  bf16x8 qf[2][2];
#pragma unroll
  for (int qt = 0; qt < 2; ++qt) {
    const ushort_t* qp = Q + ((size_t)b * N + q0 + qt * 16 + c16) * qs + q_ch + h * 64;
    qf[qt][0] = *(const bf16x8*)&qp[quad * 8];
    qf[qt][1] = *(const bf16x8*)&qp[32 + quad * 8];
  }
  const ushort_t* kbase = Kg + ((size_t)b * N) * ks + k_ch + h * 64;
  const ushort_t* vbase = vT + ((size_t)(b * H + h) * 64) * N;

  f32x4 oacc[2][4];
#pragma unroll
  for (int qt = 0; qt < 2; ++qt)
#pragma unroll
    for (int dt = 0; dt < 4; ++dt) oacc[qt][dt] = (f32x4){0.f, 0.f, 0.f, 0.f};
  float m_cur[2] = {-1e30f, -1e30f}, l_cur[2] = {0.f, 0.f};

  for (int s0 = 0; s0 < N; s0 += 64) {
    __syncthreads();
#pragma unroll
    for (int p = 0; p < 4; ++p) {
      int wp = p * 4 + wave;
      int lc = ((wp & 3) << 6) + lane;
      int row = lc >> 2, e8 = (lc & 3) * 8;
      if (wp < 4)       gl_lds16(kbase + (size_t)(s0 + row) * ks + e8,      &Ka[lc * 8]);
      else if (wp < 8)  gl_lds16(kbase + (size_t)(s0 + row) * ks + 32 + e8, &Kb2[lc * 8]);
      else if (wp < 12) gl_lds16(vbase + (size_t)row * N + s0 + e8,         &Va[lc * 8]);
      else              gl_lds16(vbase + (size_t)row * N + s0 + 32 + e8,    &Vb2[lc * 8]);
    }
    __syncthreads();

    // S^T tiles: A = K rows (m = key), B = Q rows (n = query). Scale folded in Q.
    f32x4 st[4][2];
#pragma unroll
    for (int si = 0; si < 4; ++si) {
      bf16x8 kf0 = *(const bf16x8*)&Ka[(si * 16 + c16) * 32 + quad * 8];
      bf16x8 kf1 = *(const bf16x8*)&Kb2[(si * 16 + c16) * 32 + quad * 8];
#pragma unroll
      for (int qt = 0; qt < 2; ++qt) {
        f32x4 z = (f32x4){0.f, 0.f, 0.f, 0.f};
        z = mfma16(kf0, qf[qt][0], z);
        z = mfma16(kf1, qf[qt][1], z);
        st[si][qt] = z;
      }
    }

#pragma unroll
    for (int qt = 0; qt < 2; ++qt) {
      float mx = -1e30f;
#pragma unroll
      for (int si = 0; si < 4; ++si) {
        mx = fmaxf(mx, fmaxf(fmaxf(st[si][qt][0], st[si][qt][1]),
                             fmaxf(st[si][qt][2], st[si][qt][3])));
      }
      mx = fmaxf(mx, __shfl_xor(mx, 16));
      mx = fmaxf(mx, __shfl_xor(mx, 32));
      float m_new = fmaxf(m_cur[qt], mx);
      float alpha = __expf(m_cur[qt] - m_new);
      float tsum = 0.f;
#pragma unroll
      for (int si = 0; si < 4; ++si) {
        float p0 = __expf(st[si][qt][0] - m_new);
        float p1 = __expf(st[si][qt][1] - m_new);
        float p2 = __expf(st[si][qt][2] - m_new);
        float p3 = __expf(st[si][qt][3] - m_new);
        tsum += (p0 + p1) + (p2 + p3);
        uint2 pk;
        pk.x = pk_bf16(p0, p1);
        pk.y = pk_bf16(p2, p3);
        *(uint2*)&Pt[wave][(qt * 16 + c16) * 72 + si * 16 + quad * 4] = pk;
      }
      tsum += __shfl_xor(tsum, 16);
      tsum += __shfl_xor(tsum, 32);
      l_cur[qt] = l_cur[qt] * alpha + tsum;
      m_cur[qt] = m_new;
#pragma unroll
      for (int r = 0; r < 4; ++r) {
        float ar = __shfl(alpha, quad * 4 + r);
#pragma unroll
        for (int dt = 0; dt < 4; ++dt) oacc[qt][dt][r] *= ar;
      }
    }
    __syncthreads();

#pragma unroll
    for (int qt = 0; qt < 2; ++qt) {
      bf16x8 pf0 = *(const bf16x8*)&Pt[wave][(qt * 16 + c16) * 72 + quad * 8];
      bf16x8 pf1 = *(const bf16x8*)&Pt[wave][(qt * 16 + c16) * 72 + 32 + quad * 8];
#pragma unroll
      for (int dt = 0; dt < 4; ++dt) {
        bf16x8 vf0 = *(const bf16x8*)&Va[(dt * 16 + c16) * 32 + quad * 8];
        bf16x8 vf1 = *(const bf16x8*)&Vb2[(dt * 16 + c16) * 32 + quad * 8];
        oacc[qt][dt] = mfma16(pf0, vf0, oacc[qt][dt]);
        oacc[qt][dt] = mfma16(pf1, vf1, oacc[qt][dt]);
      }
    }
  }

#pragma unroll
  for (int qt = 0; qt < 2; ++qt)
#pragma unroll
    for (int r = 0; r < 4; ++r) {
      float inv = 1.f / __shfl(l_cur[qt], quad * 4 + r);
      size_t row = q0 + qt * 16 + quad * 4 + r;
      ushort_t* op = O + ((size_t)b * N + row) * os + o_ch + h * 64;
#pragma unroll
      for (int dt = 0; dt < 4; ++dt)
        op[dt * 16 + c16] = f2bf(oacc[qt][dt][r] * inv);
    }
}

// ---------------------------------------------------------------------------
// V transpose: in [B*N][ld] bf16 (channel ch, head h) -> out [B*H][64][N]
// ---------------------------------------------------------------------------
__global__ __launch_bounds__(256)
void transpose_v(const ushort_t* __restrict__ in, int ld, int ch,
                 ushort_t* __restrict__ out, int N, int H)
{
  __shared__ __align__(16) ushort_t T[64][72];
  const int s0 = blockIdx.x * 64, h = blockIdx.y, b = blockIdx.z;
  const int tid = threadIdx.x;
#pragma unroll
  for (int p = 0; p < 2; ++p) {
    int c = p * 256 + tid;
    int sr = c >> 3, d0 = (c & 7) * 8;
    *(uint4*)&T[sr][d0] =
        *(const uint4*)&in[((size_t)b * N + s0 + sr) * ld + ch + h * 64 + d0];
  }
  __syncthreads();
  const int d = tid >> 2, sp = (tid & 3) * 16;
  union { uint4 v; ushort_t u[8]; } A, B;
#pragma unroll
  for (int j = 0; j < 8; ++j) { A.u[j] = T[sp + j][d]; B.u[j] = T[sp + 8 + j][d]; }
  ushort_t* op = out + ((size_t)(b * H + h) * 64 + d) * N + s0 + sp;
  *(uint4*)&op[0] = A.v;
  *(uint4*)&op[8] = B.v;
}

// ---------------------------------------------------------------------------
// hifi window attention (2x2 windows, 4 heads). qkv rows stride ld; per-token
// layout [3][4 heads][64]. Output stride 512, cols 0..255.
// ---------------------------------------------------------------------------
__global__ __launch_bounds__(256)
void hifi_win(const ushort_t* __restrict__ qkv, int ld, ushort_t* __restrict__ out)
{
  const int bg = blockIdx.x;
  const int b = bg >> 8, g = bg & 255;
  const int head = threadIdx.x >> 6, lane = threadIdx.x & 63;
  const int gh = g >> 4, gw = g & 15;

  int n[4];
  float q[4], k[4], v[4];
#pragma unroll
  for (int t = 0; t < 4; ++t) {
    n[t] = (gh * 2 + (t >> 1)) * 32 + gw * 2 + (t & 1);
    size_t base = ((size_t)b * 1024 + n[t]) * ld + head * 64 + lane;
    q[t] = bf2f(qkv[base]);
    k[t] = bf2f(qkv[base + 256]);
    v[t] = bf2f(qkv[base + 512]);
  }
  float sc[4][4];
#pragma unroll
  for (int t = 0; t < 4; ++t)
#pragma unroll
    for (int s = 0; s < 4; ++s) {
      float p = q[t] * k[s];
#pragma unroll
      for (int off = 32; off >= 1; off >>= 1) p += __shfl_xor(p, off);
      sc[t][s] = p * 0.125f;
    }
#pragma unroll
  for (int t = 0; t < 4; ++t) {
    float m = fmaxf(fmaxf(sc[t][0], sc[t][1]), fmaxf(sc[t][2], sc[t][3]));
    float p0 = __expf(sc[t][0] - m), p1 = __expf(sc[t][1] - m);
    float p2 = __expf(sc[t][2] - m), p3 = __expf(sc[t][3] - m);
    float sum = p0 + p1 + p2 + p3;
    float o = (p0 * v[0] + p1 * v[1] + p2 * v[2] + p3 * v[3]) / sum;
    out[((size_t)b * 1024 + n[t]) * 512 + head * 64 + lane] = f2bf(o);
  }
}

// ---------------------------------------------------------------------------
// Merged weight prep: 7 transposes W[K][N] fp32 -> WT[N][K] bf16 in one launch.
// ---------------------------------------------------------------------------
struct WEnt { const float* W; ushort_t* WT; int K; int N; };
struct WArgs { WEnt e[7]; };

__global__ __launch_bounds__(256)
void w_prep(WArgs a)
{
  WEnt w = a.e[blockIdx.z];
  if ((int)blockIdx.x >= (w.K >> 6) || (int)blockIdx.y >= (w.N >> 6)) return;
  __shared__ float T[64][65];
  const int k0 = blockIdx.x * 64, n0 = blockIdx.y * 64;
  const int tid = threadIdx.x;
#pragma unroll
  for (int p = 0; p < 4; ++p) {
    int c = p * 256 + tid;
    int kr = c >> 4, f4 = (c & 15) * 4;
    float4 v = *(const float4*)&w.W[(size_t)(k0 + kr) * w.N + n0 + f4];
    T[f4 + 0][kr] = v.x; T[f4 + 1][kr] = v.y;
    T[f4 + 2][kr] = v.z; T[f4 + 3][kr] = v.w;
  }
  __syncthreads();
  const int nl = tid >> 2, kp = (tid & 3) * 16;
  union { uint4 v; ushort_t u[8]; } A, B;
#pragma unroll
  for (int j = 0; j < 8; ++j) {
    A.u[j] = f2bf(T[nl][kp + j]);
    B.u[j] = f2bf(T[nl][kp + 8 + j]);
  }
  ushort_t* op = w.WT + (size_t)(n0 + nl) * w.K + k0 + kp;
  *(uint4*)&op[0] = A.v;
  *(uint4*)&op[8] = B.v;
}

// xpe = bf16(x + pos_emb), vectorized x4
__global__ void add_pos(const float* __restrict__ x, const float* __restrict__ pos,
                        ushort_t* __restrict__ xpe)
{
  int idx = blockIdx.x * 256 + threadIdx.x;
  int e = idx * 4;
  float4 xv = *(const float4*)&x[e];
  float4 pv = *(const float4*)&pos[e & (512 * 1024 - 1)];
  uint2 pk;
  pk.x = pk_bf16(xv.x + pv.x, xv.y + pv.y);
  pk.y = pk_bf16(xv.z + pv.z, xv.w + pv.w);
  *(uint2*)&xpe[e] = pk;
}

extern "C" void kernel_launch(void* const* d_in, const int* in_sizes, int n_in,
                              void* d_out, int out_size, void* d_ws, size_t ws_size,
                              hipStream_t stream)
{
  const float* x         = (const float*)d_in[0];
  const float* pos       = (const float*)d_in[1];
  const float* l_q_w     = (const float*)d_in[2];
  const float* l_kv_w    = (const float*)d_in[3];
  const float* l_proj_w  = (const float*)d_in[4];
  const float* l_proj_b  = (const float*)d_in[5];
  const float* h_qkv_w   = (const float*)d_in[6];
  const float* h_proj_w  = (const float*)d_in[7];
  const float* h_proj_b  = (const float*)d_in[8];
  const float* in_proj_w = (const float*)d_in[9];
  const float* in_proj_b = (const float*)d_in[10];
  const float* out_proj_w= (const float*)d_in[11];
  const float* out_proj_b= (const float*)d_in[12];
  float* out = (float*)d_out;

  char* ws = (char*)d_ws;
  ushort_t* xpe = (ushort_t*)(ws);                       // 16 MB @ 0
  ushort_t* y   = (ushort_t*)(ws + (size_t)16777216);    // 16 MB @ 16M
  ushort_t* F   = (ushort_t*)(ws + (size_t)33554432);    // 48 MB @ 32M (fused acts)
  ushort_t* rB  = (ushort_t*)(ws + (size_t)83886080);    // 16 MB @ 80M
  ushort_t* wb  = (ushort_t*)(ws + (size_t)100663296);   // ~4 MB @ 96M (weights)

  // fused BT for the xpe GEMM: rows [0,768)=h_qkv, [768,1024)=l_q, [1024,1536)=l_kv
  ushort_t* F_T      = wb;                        // 1536 x 512
  ushort_t* h_projT  = wb + 786432;               // 256 x 256
  ushort_t* l_projT  = wb + 851968;               // 256 x 256
  ushort_t* in_projT = wb + 917504;               // 1536 x 512
  ushort_t* out_projT= wb + 1703936;              // 512 x 512

  const int M = 16384;
  ushort_t* vT_lo = xpe;   // 8 MB; xpe dead after fused GEMM
  ushort_t* vT_m  = rB;    // 16 MB; rB dead after lproj

  WArgs wa;
  wa.e[0] = {h_qkv_w,   F_T,                 512, 768};
  wa.e[1] = {l_q_w,     F_T + 768 * 512,     512, 256};
  wa.e[2] = {l_kv_w,    F_T + 1024 * 512,    512, 512};
  wa.e[3] = {h_proj_w,  h_projT,             256, 256};
  wa.e[4] = {l_proj_w,  l_projT,             256, 256};
  wa.e[5] = {in_proj_w, in_projT,            512, 1536};
  wa.e[6] = {out_proj_w,out_projT,           512, 512};
  w_prep<<<dim3(8, 24, 7), dim3(256), 0, stream>>>(wa);

  add_pos<<<dim3(8192), dim3(256), 0, stream>>>(x, pos, xpe);

  // 1. fused qkv GEMM: [M,512] x [512,1536] -> F (lofi q cols pre-scaled)
  gemm_bt<<<dim3(M / 128, 12), dim3(256), 0, stream>>>(
      xpe, 512, F_T, nullptr, F, nullptr, 1536, 0, 512, 768, 1024);
  // 2. hifi window attention -> rB cols [0,256)
  hifi_win<<<dim3(4096), dim3(256), 0, stream>>>(F, 1536, rB);
  // 3. transpose lofi V (F cols 1280..1535) -> vT_lo (xpe region, now dead)
  transpose_v<<<dim3(16, 4, 16), dim3(256), 0, stream>>>(
      F, 1536, 1280, vT_lo, 1024, 4);
  // 4. lofi attention (4 heads) -> rB cols [256,512)
  flash_attn3<<<dim3(8, 4, 16), dim3(256), 0, stream>>>(
      F, 1536, 768, F, 1536, 1024, vT_lo, rB, 512, 256, 1024);
  // 5. hifi proj -> y[:, 0:256)
  gemm_bt<<<dim3(M / 128, 2), dim3(256), 0, stream>>>(
      rB, 512, h_projT, h_proj_b, y, nullptr, 512, 0, 256, 0, 0);
  // 6. lofi proj -> y[:, 256:512)
  gemm_bt<<<dim3(M / 128, 2), dim3(256), 0, stream>>>(
      rB + 256, 512, l_projT, l_proj_b, y, nullptr, 512, 256, 256, 0, 0);
  // 7. mha qkv: [M,512] x [512,1536] -> F (q cols pre-scaled)
  gemm_bt<<<dim3(M / 128, 12), dim3(256), 0, stream>>>(
      y, 512, in_projT, in_proj_b, F, nullptr, 1536, 0, 512, 0, 512);
  // 8. transpose mha V (F cols 1024..1535) -> vT_m (rB dead now)
  transpose_v<<<dim3(16, 8, 16), dim3(256), 0, stream>>>(
      F, 1536, 1024, vT_m, 1024, 8);
  // 9. mha attention (8 heads) -> xpe region [M,512] (vT_lo dead after step 4)
  flash_attn3<<<dim3(8, 8, 16), dim3(256), 0, stream>>>(
      F, 1536, 0, F, 1536, 512, vT_m, xpe, 512, 0, 1024);
  // 10. out proj -> d_out fp32
  gemm_bt<<<dim3(M / 128, 4), dim3(256), 0, stream>>>(
      xpe, 512, out_projT, out_proj_b, nullptr, out, 512, 0, 512, 0, 0);
}

// Round 5
// 393.891 us; speedup vs baseline: 1.4135x; 1.0025x over previous
//
#include <hip/hip_runtime.h>

typedef unsigned short ushort_t;
typedef short bf16x8 __attribute__((ext_vector_type(8)));
typedef float f32x4 __attribute__((ext_vector_type(4)));

#define DEV __device__ __forceinline__

// round-half-up bf16 (2 ops)
DEV ushort_t f2bf(float f) {
  return (ushort_t)((__float_as_uint(f) + 0x8000u) >> 16);
}
// pack two floats -> 2 bf16 in one u32 (3 ops: add, add, v_perm_b32)
DEV unsigned pk_bf16(float lo, float hi) {
  unsigned a = __float_as_uint(lo) + 0x8000u;
  unsigned b = __float_as_uint(hi) + 0x8000u;
  return __builtin_amdgcn_perm(b, a, 0x07060302);  // {b.hi16, a.hi16}
}
DEV float bf2f(ushort_t h) {
  union { unsigned int u; float f; } v; v.u = ((unsigned int)h) << 16;
  return v.f;
}
DEV f32x4 mfma16(bf16x8 a, bf16x8 b, f32x4 c) {
  return __builtin_amdgcn_mfma_f32_16x16x32_bf16(a, b, c, 0, 0, 0);
}
typedef __attribute__((address_space(3))) void lds_void;
typedef const __attribute__((address_space(1))) void glb_void;
DEV void gl_lds16(const void* g, void* l) {
  __builtin_amdgcn_global_load_lds((glb_void*)g, (lds_void*)l, 16, 0, 0);
}

// ---------------------------------------------------------------------------
// bf16 GEMM: C = A[M,K] * BT[N,K]^T (+bias). 128x128 tile, 4 waves, 4x4 MFMA.
// Columns in [sc_lo, sc_hi) get multiplied by scv after bias (Q pre-scaling).
// ---------------------------------------------------------------------------
__global__ __launch_bounds__(256)
void gemm_bt(const ushort_t* __restrict__ A, int lda,
             const ushort_t* __restrict__ BT,
             const float* __restrict__ bias,
             ushort_t* __restrict__ Cb, float* __restrict__ Cf,
             int ldc, int coff, int K, float scv, int sc_lo, int sc_hi)
{
  __shared__ __align__(16) ushort_t As[128 * 32];
  __shared__ __align__(16) ushort_t Bs[128 * 32];
  const int tid  = threadIdx.x;
  const int wave = tid >> 6, lane = tid & 63;
  const int quad = lane >> 4, r16 = lane & 15;
  const int m0 = blockIdx.x * 128, n0 = blockIdx.y * 128;
  const int wm = (wave >> 1) * 64, wn = (wave & 1) * 64;

  f32x4 acc[4][4];
#pragma unroll
  for (int i = 0; i < 4; ++i)
#pragma unroll
    for (int j = 0; j < 4; ++j) acc[i][j] = (f32x4){0.f, 0.f, 0.f, 0.f};

  for (int kc = 0; kc < K; kc += 32) {
#pragma unroll
    for (int p = 0; p < 4; ++p) {
      int wp = p * 4 + wave;                 // 0..15; 0..7 -> As, 8..15 -> Bs
      int lc = ((wp & 7) << 6) + lane;       // chunk 0..511 within array
      int row = lc >> 2, e8 = (lc & 3) * 8;
      if (wp < 8) gl_lds16(&A[(size_t)(m0 + row) * lda + kc + e8], &As[lc * 8]);
      else        gl_lds16(&BT[(size_t)(n0 + row) * K  + kc + e8], &Bs[lc * 8]);
    }
    __syncthreads();
    bf16x8 af[4], bfr[4];
#pragma unroll
    for (int i = 0; i < 4; ++i) {
      af[i]  = *(const bf16x8*)&As[(wm + i * 16 + r16) * 32 + quad * 8];
      bfr[i] = *(const bf16x8*)&Bs[(wn + i * 16 + r16) * 32 + quad * 8];
    }
#pragma unroll
    for (int mi = 0; mi < 4; ++mi)
#pragma unroll
      for (int ni = 0; ni < 4; ++ni)
        acc[mi][ni] = mfma16(af[mi], bfr[ni], acc[mi][ni]);
    __syncthreads();
  }

  // C/D layout: col = lane&15, row = quad*4 + reg  [m89/m91]
#pragma unroll
  for (int mi = 0; mi < 4; ++mi) {
#pragma unroll
    for (int ni = 0; ni < 4; ++ni) {
      int col = n0 + wn + ni * 16 + r16;
      float bv = bias ? bias[col] : 0.f;
      float s = (col >= sc_lo && col < sc_hi) ? scv : 1.0f;
#pragma unroll
      for (int r = 0; r < 4; ++r) {
        int row = m0 + wm + mi * 16 + quad * 4 + r;
        float v = (acc[mi][ni][r] + bv) * s;
        if (Cf) Cf[(size_t)row * ldc + coff + col] = v;
        else    Cb[(size_t)row * ldc + coff + col] = f2bf(v);
      }
    }
  }
}

// ---------------------------------------------------------------------------
// Flash attention v5. Block = 4 waves x 32 queries. Key tile 64, double-
// buffered K/V staging via global_load_lds -> ONE barrier per iteration.
// Q pre-scaled by 0.125 (exact in bf16). S^T = mfma(A=K, B=Q) -> query on
// lane&15. P reaches the PV B-operand layout via 16 bpermute + 8 selects
// (dest-indexed register picked by dest quad — fixes R3's source-eval bug).
// PV computes O^T = mfma(A=V^T, B=P): m/l/alpha/O all in query=lane&15 view.
// ---------------------------------------------------------------------------
__global__ __launch_bounds__(256)
void flash_attn5(const ushort_t* __restrict__ Q, int qs, int q_ch,
                 const ushort_t* __restrict__ Kg, int ks, int k_ch,
                 const ushort_t* __restrict__ vT,
                 ushort_t* __restrict__ O, int os, int o_ch,
                 int N)
{
  // [buf][half][64 rows][32 cols] ; K halves split d, V^T halves split keys
  __shared__ __align__(16) ushort_t Ks[2][2][64 * 32];
  __shared__ __align__(16) ushort_t Vs[2][2][64 * 32];

  const int b = blockIdx.z, h = blockIdx.y, H = gridDim.y;
  const int tid = threadIdx.x, wave = tid >> 6, lane = tid & 63;
  const int quad = lane >> 4, c16 = lane & 15;
  const int q0 = blockIdx.x * 128 + wave * 32;

  bf16x8 qf[2][2];
#pragma unroll
  for (int qt = 0; qt < 2; ++qt) {
    const ushort_t* qp = Q + ((size_t)b * N + q0 + qt * 16 + c16) * qs + q_ch + h * 64;
    qf[qt][0] = *(const bf16x8*)&qp[quad * 8];
    qf[qt][1] = *(const bf16x8*)&qp[32 + quad * 8];
  }
  const ushort_t* kbase = Kg + ((size_t)b * N) * ks + k_ch + h * 64;
  const ushort_t* vbase = vT + ((size_t)(b * H + h) * 64) * N;

  f32x4 oacc[2][4];
#pragma unroll
  for (int qt = 0; qt < 2; ++qt)
#pragma unroll
    for (int dt = 0; dt < 4; ++dt) oacc[qt][dt] = (f32x4){0.f, 0.f, 0.f, 0.f};
  float m_cur[2] = {-1e30f, -1e30f}, l_cur[2] = {0.f, 0.f};

  // bpermute source lanes for the P layout transform:
  // element i of dest quad comes from quad_s = (2*(quad&1) + (i>>1))  [i<2 -> A, i>=2 -> B]
  const int laneA = (2 * (quad & 1)) * 16 + c16;
  const int laneB = laneA + 16;

  auto stage = [&](int s0, int buf) {
#pragma unroll
    for (int p = 0; p < 4; ++p) {
      int wp = p * 4 + wave;                 // 0..15
      int lc = ((wp & 3) << 6) + lane;       // 0..255 within a half-array
      int row = lc >> 2, e8 = (lc & 3) * 8;
      if (wp < 4)       gl_lds16(kbase + (size_t)(s0 + row) * ks + e8,      &Ks[buf][0][lc * 8]);
      else if (wp < 8)  gl_lds16(kbase + (size_t)(s0 + row) * ks + 32 + e8, &Ks[buf][1][lc * 8]);
      else if (wp < 12) gl_lds16(vbase + (size_t)row * N + s0 + e8,         &Vs[buf][0][lc * 8]);
      else              gl_lds16(vbase + (size_t)row * N + s0 + 32 + e8,    &Vs[buf][1][lc * 8]);
    }
  };

  stage(0, 0);
  const int NT = N >> 6;
  for (int it = 0; it < NT; ++it) {
    const int cur = it & 1;
    __syncthreads();                     // vmcnt(0) drain: tile `it` staged;
                                         // also fences prev-iter LDS readers
    if (it + 1 < NT) stage((it + 1) << 6, cur ^ 1);

    // S^T: A = K rows (m=key si*16+quad*4+r), B = Q (n=query c16).
    f32x4 st[4][2];
#pragma unroll
    for (int si = 0; si < 4; ++si) {
      bf16x8 kf0 = *(const bf16x8*)&Ks[cur][0][(si * 16 + c16) * 32 + quad * 8];
      bf16x8 kf1 = *(const bf16x8*)&Ks[cur][1][(si * 16 + c16) * 32 + quad * 8];
#pragma unroll
      for (int qt = 0; qt < 2; ++qt) {
        f32x4 z = (f32x4){0.f, 0.f, 0.f, 0.f};
        z = mfma16(kf0, qf[qt][0], z);
        z = mfma16(kf1, qf[qt][1], z);
        st[si][qt] = z;
      }
    }

#pragma unroll
    for (int qt = 0; qt < 2; ++qt) {
      float mx = -1e30f;
#pragma unroll
      for (int si = 0; si < 4; ++si)
        mx = fmaxf(mx, fmaxf(fmaxf(st[si][qt][0], st[si][qt][1]),
                             fmaxf(st[si][qt][2], st[si][qt][3])));
      mx = fmaxf(mx, __shfl_xor(mx, 16));
      mx = fmaxf(mx, __shfl_xor(mx, 32));
      float m_new = fmaxf(m_cur[qt], mx);
      float alpha = __expf(m_cur[qt] - m_new);
      m_cur[qt] = m_new;

      float tsum = 0.f;
      unsigned pks[4][2];
#pragma unroll
      for (int si = 0; si < 4; ++si) {
        float p0 = __expf(st[si][qt][0] - m_new);
        float p1 = __expf(st[si][qt][1] - m_new);
        float p2 = __expf(st[si][qt][2] - m_new);
        float p3 = __expf(st[si][qt][3] - m_new);
        tsum += (p0 + p1) + (p2 + p3);
        pks[si][0] = pk_bf16(p0, p1);      // keys si*16+quad*4+{0,1}
        pks[si][1] = pk_bf16(p2, p3);      // keys si*16+quad*4+{2,3}
      }
      tsum += __shfl_xor(tsum, 16);
      tsum += __shfl_xor(tsum, 32);
      l_cur[qt] = l_cur[qt] * alpha + tsum;

      // rescale O^T (this lane's elements all belong to query c16) — no shfl
#pragma unroll
      for (int dt = 0; dt < 4; ++dt) {
        oacc[qt][dt][0] *= alpha; oacc[qt][dt][1] *= alpha;
        oacc[qt][dt][2] *= alpha; oacc[qt][dt][3] *= alpha;
      }

      // P -> PV B-operand: B[n=query=c16][k=key=quad*8+j]. Element i (u32,
      // keys {F*32+quad*8+2i, +1}) comes from src lane quad_s=2*(quad&1)+(i>>1)
      // register pks[2F + (quad>>1)][i&1]. Pull BOTH si candidates, select by
      // DEST quad (R3 bug: source evaluated its own index).
      union U8 { bf16x8 f; unsigned u[4]; } pf0, pf1;
      const bool hiq = quad >= 2;
#pragma unroll
      for (int i = 0; i < 4; ++i) {
        int src = (i < 2) ? laneA : laneB;
        unsigned a0 = __shfl(pks[0][i & 1], src);
        unsigned a1 = __shfl(pks[1][i & 1], src);
        unsigned a2 = __shfl(pks[2][i & 1], src);
        unsigned a3 = __shfl(pks[3][i & 1], src);
        pf0.u[i] = hiq ? a1 : a0;
        pf1.u[i] = hiq ? a3 : a2;
      }

      // PV: O^T = mfma(A = V^T (m=d), B = P (n=query))
#pragma unroll
      for (int dt = 0; dt < 4; ++dt) {
        bf16x8 vf0 = *(const bf16x8*)&Vs[cur][0][(dt * 16 + c16) * 32 + quad * 8];
        bf16x8 vf1 = *(const bf16x8*)&Vs[cur][1][(dt * 16 + c16) * 32 + quad * 8];
        oacc[qt][dt] = mfma16(vf0, pf0.f, oacc[qt][dt]);
        oacc[qt][dt] = mfma16(vf1, pf1.f, oacc[qt][dt]);
      }
    }
  }

  // epilogue: O^T element r = O[query c16][d = dt*16 + quad*4 + r]
#pragma unroll
  for (int qt = 0; qt < 2; ++qt) {
    float inv = 1.f / l_cur[qt];
    ushort_t* op = O + ((size_t)b * N + q0 + qt * 16 + c16) * os + o_ch + h * 64;
#pragma unroll
    for (int dt = 0; dt < 4; ++dt) {
      uint2 pkv;
      pkv.x = pk_bf16(oacc[qt][dt][0] * inv, oacc[qt][dt][1] * inv);
      pkv.y = pk_bf16(oacc[qt][dt][2] * inv, oacc[qt][dt][3] * inv);
      *(uint2*)&op[dt * 16 + quad * 4] = pkv;
    }
  }
}

// ---------------------------------------------------------------------------
// V transpose: in [B*N][ld] bf16 (channel ch, head h) -> out [B*H][64][N]
// ---------------------------------------------------------------------------
__global__ __launch_bounds__(256)
void transpose_v(const ushort_t* __restrict__ in, int ld, int ch,
                 ushort_t* __restrict__ out, int N, int H)
{
  __shared__ __align__(16) ushort_t T[64][72];
  const int s0 = blockIdx.x * 64, h = blockIdx.y, b = blockIdx.z;
  const int tid = threadIdx.x;
#pragma unroll
  for (int p = 0; p < 2; ++p) {
    int c = p * 256 + tid;
    int sr = c >> 3, d0 = (c & 7) * 8;
    *(uint4*)&T[sr][d0] =
        *(const uint4*)&in[((size_t)b * N + s0 + sr) * ld + ch + h * 64 + d0];
  }
  __syncthreads();
  const int d = tid >> 2, sp = (tid & 3) * 16;
  union { uint4 v; ushort_t u[8]; } A, B;
#pragma unroll
  for (int j = 0; j < 8; ++j) { A.u[j] = T[sp + j][d]; B.u[j] = T[sp + 8 + j][d]; }
  ushort_t* op = out + ((size_t)(b * H + h) * 64 + d) * N + s0 + sp;
  *(uint4*)&op[0] = A.v;
  *(uint4*)&op[8] = B.v;
}

// ---------------------------------------------------------------------------
// hifi window attention (2x2 windows, 4 heads). qkv rows stride ld; per-token
// layout [3][4 heads][64]. Output stride 512, cols 0..255.
// ---------------------------------------------------------------------------
__global__ __launch_bounds__(256)
void hifi_win(const ushort_t* __restrict__ qkv, int ld, ushort_t* __restrict__ out)
{
  const int bg = blockIdx.x;
  const int b = bg >> 8, g = bg & 255;
  const int head = threadIdx.x >> 6, lane = threadIdx.x & 63;
  const int gh = g >> 4, gw = g & 15;

  int n[4];
  float q[4], k[4], v[4];
#pragma unroll
  for (int t = 0; t < 4; ++t) {
    n[t] = (gh * 2 + (t >> 1)) * 32 + gw * 2 + (t & 1);
    size_t base = ((size_t)b * 1024 + n[t]) * ld + head * 64 + lane;
    q[t] = bf2f(qkv[base]);
    k[t] = bf2f(qkv[base + 256]);
    v[t] = bf2f(qkv[base + 512]);
  }
  float sc[4][4];
#pragma unroll
  for (int t = 0; t < 4; ++t)
#pragma unroll
    for (int s = 0; s < 4; ++s) {
      float p = q[t] * k[s];
#pragma unroll
      for (int off = 32; off >= 1; off >>= 1) p += __shfl_xor(p, off);
      sc[t][s] = p * 0.125f;
    }
#pragma unroll
  for (int t = 0; t < 4; ++t) {
    float m = fmaxf(fmaxf(sc[t][0], sc[t][1]), fmaxf(sc[t][2], sc[t][3]));
    float p0 = __expf(sc[t][0] - m), p1 = __expf(sc[t][1] - m);
    float p2 = __expf(sc[t][2] - m), p3 = __expf(sc[t][3] - m);
    float sum = p0 + p1 + p2 + p3;
    float o = (p0 * v[0] + p1 * v[1] + p2 * v[2] + p3 * v[3]) / sum;
    out[((size_t)b * 1024 + n[t]) * 512 + head * 64 + lane] = f2bf(o);
  }
}

// ---------------------------------------------------------------------------
// Merged weight prep: 7 transposes W[K][N] fp32 -> WT[N][K] bf16 in one launch.
// ---------------------------------------------------------------------------
struct WEnt { const float* W; ushort_t* WT; int K; int N; };
struct WArgs { WEnt e[7]; };

__global__ __launch_bounds__(256)
void w_prep(WArgs a)
{
  WEnt w = a.e[blockIdx.z];
  if ((int)blockIdx.x >= (w.K >> 6) || (int)blockIdx.y >= (w.N >> 6)) return;
  __shared__ float T[64][65];
  const int k0 = blockIdx.x * 64, n0 = blockIdx.y * 64;
  const int tid = threadIdx.x;
#pragma unroll
  for (int p = 0; p < 4; ++p) {
    int c = p * 256 + tid;
    int kr = c >> 4, f4 = (c & 15) * 4;
    float4 v = *(const float4*)&w.W[(size_t)(k0 + kr) * w.N + n0 + f4];
    T[f4 + 0][kr] = v.x; T[f4 + 1][kr] = v.y;
    T[f4 + 2][kr] = v.z; T[f4 + 3][kr] = v.w;
  }
  __syncthreads();
  const int nl = tid >> 2, kp = (tid & 3) * 16;
  union { uint4 v; ushort_t u[8]; } A, B;
#pragma unroll
  for (int j = 0; j < 8; ++j) {
    A.u[j] = f2bf(T[nl][kp + j]);
    B.u[j] = f2bf(T[nl][kp + 8 + j]);
  }
  ushort_t* op = w.WT + (size_t)(n0 + nl) * w.K + k0 + kp;
  *(uint4*)&op[0] = A.v;
  *(uint4*)&op[8] = B.v;
}

// xpe = bf16(x + pos_emb), vectorized x4
__global__ void add_pos(const float* __restrict__ x, const float* __restrict__ pos,
                        ushort_t* __restrict__ xpe)
{
  int idx = blockIdx.x * 256 + threadIdx.x;
  int e = idx * 4;
  float4 xv = *(const float4*)&x[e];
  float4 pv = *(const float4*)&pos[e & (512 * 1024 - 1)];
  uint2 pk;
  pk.x = pk_bf16(xv.x + pv.x, xv.y + pv.y);
  pk.y = pk_bf16(xv.z + pv.z, xv.w + pv.w);
  *(uint2*)&xpe[e] = pk;
}

extern "C" void kernel_launch(void* const* d_in, const int* in_sizes, int n_in,
                              void* d_out, int out_size, void* d_ws, size_t ws_size,
                              hipStream_t stream)
{
  const float* x         = (const float*)d_in[0];
  const float* pos       = (const float*)d_in[1];
  const float* l_q_w     = (const float*)d_in[2];
  const float* l_kv_w    = (const float*)d_in[3];
  const float* l_proj_w  = (const float*)d_in[4];
  const float* l_proj_b  = (const float*)d_in[5];
  const float* h_qkv_w   = (const float*)d_in[6];
  const float* h_proj_w  = (const float*)d_in[7];
  const float* h_proj_b  = (const float*)d_in[8];
  const float* in_proj_w = (const float*)d_in[9];
  const float* in_proj_b = (const float*)d_in[10];
  const float* out_proj_w= (const float*)d_in[11];
  const float* out_proj_b= (const float*)d_in[12];
  float* out = (float*)d_out;

  const float QSCALE = 0.125f;   // exact in bf16 — no extra rounding on Q

  char* ws = (char*)d_ws;
  ushort_t* xpe = (ushort_t*)(ws);                       // 16 MB @ 0
  ushort_t* y   = (ushort_t*)(ws + (size_t)16777216);    // 16 MB @ 16M
  ushort_t* F   = (ushort_t*)(ws + (size_t)33554432);    // 48 MB @ 32M (fused acts)
  ushort_t* rB  = (ushort_t*)(ws + (size_t)83886080);    // 16 MB @ 80M
  ushort_t* wb  = (ushort_t*)(ws + (size_t)100663296);   // ~4 MB @ 96M (weights)

  // fused BT for the xpe GEMM: rows [0,768)=h_qkv, [768,1024)=l_q, [1024,1536)=l_kv
  ushort_t* F_T      = wb;                        // 1536 x 512
  ushort_t* h_projT  = wb + 786432;               // 256 x 256
  ushort_t* l_projT  = wb + 851968;               // 256 x 256
  ushort_t* in_projT = wb + 917504;               // 1536 x 512
  ushort_t* out_projT= wb + 1703936;              // 512 x 512

  const int M = 16384;
  ushort_t* vT_lo = xpe;   // 8 MB; xpe dead after fused GEMM
  ushort_t* vT_m  = rB;    // 16 MB; rB dead after lproj

  WArgs wa;
  wa.e[0] = {h_qkv_w,   F_T,                 512, 768};
  wa.e[1] = {l_q_w,     F_T + 768 * 512,     512, 256};
  wa.e[2] = {l_kv_w,    F_T + 1024 * 512,    512, 512};
  wa.e[3] = {h_proj_w,  h_projT,             256, 256};
  wa.e[4] = {l_proj_w,  l_projT,             256, 256};
  wa.e[5] = {in_proj_w, in_projT,            512, 1536};
  wa.e[6] = {out_proj_w,out_projT,           512, 512};
  w_prep<<<dim3(8, 24, 7), dim3(256), 0, stream>>>(wa);

  add_pos<<<dim3(8192), dim3(256), 0, stream>>>(x, pos, xpe);

  // 1. fused qkv GEMM: [M,512] x [512,1536] -> F (lofi q cols pre-scaled)
  gemm_bt<<<dim3(M / 128, 12), dim3(256), 0, stream>>>(
      xpe, 512, F_T, nullptr, F, nullptr, 1536, 0, 512, QSCALE, 768, 1024);
  // 2. hifi window attention -> rB cols [0,256)
  hifi_win<<<dim3(4096), dim3(256), 0, stream>>>(F, 1536, rB);
  // 3. transpose lofi V (F cols 1280..1535) -> vT_lo (xpe region, now dead)
  transpose_v<<<dim3(16, 4, 16), dim3(256), 0, stream>>>(
      F, 1536, 1280, vT_lo, 1024, 4);
  // 4. lofi attention (4 heads) -> rB cols [256,512)
  flash_attn5<<<dim3(8, 4, 16), dim3(256), 0, stream>>>(
      F, 1536, 768, F, 1536, 1024, vT_lo, rB, 512, 256, 1024);
  // 5. hifi proj -> y[:, 0:256)
  gemm_bt<<<dim3(M / 128, 2), dim3(256), 0, stream>>>(
      rB, 512, h_projT, h_proj_b, y, nullptr, 512, 0, 256, 1.0f, 0, 0);
  // 6. lofi proj -> y[:, 256:512)
  gemm_bt<<<dim3(M / 128, 2), dim3(256), 0, stream>>>(
      rB + 256, 512, l_projT, l_proj_b, y, nullptr, 512, 256, 256, 1.0f, 0, 0);
  // 7. mha qkv: [M,512] x [512,1536] -> F (q cols pre-scaled)
  gemm_bt<<<dim3(M / 128, 12), dim3(256), 0, stream>>>(
      y, 512, in_projT, in_proj_b, F, nullptr, 1536, 0, 512, QSCALE, 0, 512);
  // 8. transpose mha V (F cols 1024..1535) -> vT_m (rB dead now)
  transpose_v<<<dim3(16, 8, 16), dim3(256), 0, stream>>>(
      F, 1536, 1024, vT_m, 1024, 8);
  // 9. mha attention (8 heads) -> xpe region [M,512]
  flash_attn5<<<dim3(8, 8, 16), dim3(256), 0, stream>>>(
      F, 1536, 0, F, 1536, 512, vT_m, xpe, 512, 0, 1024);
  // 10. out proj -> d_out fp32
  gemm_bt<<<dim3(M / 128, 4), dim3(256), 0, stream>>>(
      xpe, 512, out_projT, out_proj_b, nullptr, out, 512, 0, 512, 1.0f, 0, 0);
}